// Round 1
// baseline (1054.095 us; speedup 1.0000x reference)
//
#include <hip/hip_runtime.h>
#include <stdint.h>

#define D_MODEL 1024
#define NHEAD   16
#define HDIM    64
#define FFDIM   4096
#define BATCH   4
#define SEQ     2048
#define ROWS    (BATCH*SEQ)   // 8192

typedef unsigned short u16;
typedef __bf16 bf16_t;
typedef bf16_t bf16x8 __attribute__((ext_vector_type(8)));
typedef float  f32x4  __attribute__((ext_vector_type(4)));

__device__ __forceinline__ u16 f2bf(float f) {
  union { float f; unsigned u; } v; v.f = f;
  unsigned r = v.u + 0x7fffu + ((v.u >> 16) & 1u);
  return (u16)(r >> 16);
}

__device__ __forceinline__ void gl2lds16(const void* g, void* l) {
  __builtin_amdgcn_global_load_lds((const __attribute__((address_space(1))) void*)g,
                                   (__attribute__((address_space(3))) void*)l, 16, 0, 0);
}

#define MFMA_BF16(a, b, c) __builtin_amdgcn_mfma_f32_16x16x32_bf16((a), (b), (c), 0, 0, 0)

// ---------------- LayerNorm (fp32 in -> bf16 out) ----------------
__global__ __launch_bounds__(256) void ln_kernel(const float* __restrict__ x,
                                                 const float* __restrict__ g,
                                                 const float* __restrict__ be,
                                                 u16* __restrict__ out) {
  __shared__ float red[10];
  int row = blockIdx.x;
  int t = threadIdx.x;
  const float* xr = x + (size_t)row * D_MODEL;
  float4 xv = ((const float4*)xr)[t];
  float s  = xv.x + xv.y + xv.z + xv.w;
  float s2 = xv.x*xv.x + xv.y*xv.y + xv.z*xv.z + xv.w*xv.w;
  for (int d = 32; d > 0; d >>= 1) { s += __shfl_down(s, d); s2 += __shfl_down(s2, d); }
  int wid = t >> 6;
  if ((t & 63) == 0) { red[wid*2] = s; red[wid*2+1] = s2; }
  __syncthreads();
  if (t == 0) {
    float a = 0.f, b2 = 0.f;
    for (int i = 0; i < 4; ++i) { a += red[i*2]; b2 += red[i*2+1]; }
    red[8] = a; red[9] = b2;
  }
  __syncthreads();
  float mu  = red[8] * (1.0f / D_MODEL);
  float var = red[9] * (1.0f / D_MODEL) - mu*mu;
  float rstd = rsqrtf(var + 1e-12f);
  float4 gv = ((const float4*)g)[t];
  float4 bv = ((const float4*)be)[t];
  unsigned long long o =
      (unsigned long long)f2bf((xv.x - mu) * rstd * gv.x + bv.x)
    | ((unsigned long long)f2bf((xv.y - mu) * rstd * gv.y + bv.y) << 16)
    | ((unsigned long long)f2bf((xv.z - mu) * rstd * gv.z + bv.z) << 32)
    | ((unsigned long long)f2bf((xv.w - mu) * rstd * gv.w + bv.w) << 48);
  ((unsigned long long*)out)[(size_t)row * (D_MODEL/4) + t] = o;
}

// ---------------- Weight transpose fp32 [K,N] -> bf16 [N,K] ----------------
__global__ __launch_bounds__(256) void wt_kernel(const float* __restrict__ W,
                                                 u16* __restrict__ Wt, int K, int N) {
  __shared__ float tile[32][33];
  int n0 = blockIdx.x * 32, k0 = blockIdx.y * 32;
  int tx = threadIdx.x & 31, ty = threadIdx.x >> 5;   // ty: 0..7
  #pragma unroll
  for (int i = 0; i < 4; ++i) {
    int k = ty + i*8;
    tile[k][tx] = W[(size_t)(k0 + k) * N + n0 + tx];
  }
  __syncthreads();
  #pragma unroll
  for (int i = 0; i < 4; ++i) {
    int n = ty + i*8;
    Wt[(size_t)(n0 + n) * K + k0 + tx] = f2bf(tile[tx][n]);
  }
}

// ---------------- GEMM: C[M,N] = A[M,K] @ Bt[N,K]^T (+bias, epilogue) -------
// EPI 0: bf16 out = C + bias
// EPI 1: f32  out = resid + C + bias
// EPI 2: bf16 out = gelu(C + bias)   (exact, erf)
__device__ __forceinline__ float gelu_f(float v) {
  return 0.5f * v * (1.0f + erff(v * 0.70710678118654752f));
}

template<int EPI>
__global__ __launch_bounds__(256) void gemm_bt(const u16* __restrict__ A,
                                               const u16* __restrict__ Bt,
                                               const float* __restrict__ bias,
                                               const float* __restrict__ resid,
                                               void* __restrict__ outp,
                                               int M, int N, int K) {
  __shared__ __align__(16) u16 sA[128*32];
  __shared__ __align__(16) u16 sB[128*32];
  int tid = threadIdx.x;
  int lane = tid & 63, w = tid >> 6;
  int r = lane & 15, kg = lane >> 4;
  int wr = w >> 1, wc = w & 1;
  int bm = blockIdx.y, bn = blockIdx.x;

  f32x4 acc[4][4];
  #pragma unroll
  for (int m = 0; m < 4; ++m)
    #pragma unroll
    for (int n = 0; n < 4; ++n) acc[m][n] = f32x4{0.f, 0.f, 0.f, 0.f};

  // staging: 8 chunks of 1KB; wave w stages chunks w and w+4.
  // chunk q: rows q*16 + (lane>>2), col = (lane&3)*8 ; LDS linear [row][col], stride 32 elems
  int cr0 = w*16 + (lane >> 2), cr1 = (w+4)*16 + (lane >> 2);
  int ccol = (lane & 3) * 8;
  const u16* Ag0 = A  + (size_t)(bm*128 + cr0) * K + ccol;
  const u16* Ag1 = A  + (size_t)(bm*128 + cr1) * K + ccol;
  const u16* Bg0 = Bt + (size_t)(bn*128 + cr0) * K + ccol;
  const u16* Bg1 = Bt + (size_t)(bn*128 + cr1) * K + ccol;
  u16* lA0 = sA + w*512 + lane*8;
  u16* lA1 = sA + (w+4)*512 + lane*8;
  u16* lB0 = sB + w*512 + lane*8;
  u16* lB1 = sB + (w+4)*512 + lane*8;

  for (int k0 = 0; k0 < K; k0 += 32) {
    gl2lds16(Ag0 + k0, lA0);
    gl2lds16(Ag1 + k0, lA1);
    gl2lds16(Bg0 + k0, lB0);
    gl2lds16(Bg1 + k0, lB1);
    __syncthreads();
    bf16x8 af[4], bfr[4];
    #pragma unroll
    for (int m = 0; m < 4; ++m) af[m]  = *(const bf16x8*)&sA[(wr*64 + m*16 + r)*32 + kg*8];
    #pragma unroll
    for (int n = 0; n < 4; ++n) bfr[n] = *(const bf16x8*)&sB[(wc*64 + n*16 + r)*32 + kg*8];
    #pragma unroll
    for (int m = 0; m < 4; ++m)
      #pragma unroll
      for (int n = 0; n < 4; ++n)
        acc[m][n] = MFMA_BF16(af[m], bfr[n], acc[m][n]);
    __syncthreads();
  }

  int orow = bm*128 + wr*64, ocol = bn*128 + wc*64;
  #pragma unroll
  for (int m = 0; m < 4; ++m) {
    #pragma unroll
    for (int n = 0; n < 4; ++n) {
      #pragma unroll
      for (int j = 0; j < 4; ++j) {
        int rr = orow + m*16 + kg*4 + j;
        int cc = ocol + n*16 + r;
        size_t idx = (size_t)rr * N + cc;
        float v = acc[m][n][j] + bias[cc];
        if (EPI == 0)       ((u16*)outp)[idx]   = f2bf(v);
        else if (EPI == 1)  ((float*)outp)[idx] = resid[idx] + v;
        else                ((u16*)outp)[idx]   = f2bf(gelu_f(v));
      }
    }
  }
}

// ---------------- Flash attention: 1 wave per (b,h,16-row q tile) -----------
__global__ __launch_bounds__(64) void attn_kernel(const u16* __restrict__ qb,
                                                  const u16* __restrict__ kb,
                                                  const u16* __restrict__ vb,
                                                  const int* __restrict__ mask,
                                                  u16* __restrict__ ob) {
  __shared__ __align__(16) u16 p_lds[16*32];
  __shared__ __align__(16) u16 vt_lds[64*32];
  int lane = threadIdx.x;
  int r = lane & 15, kg = lane >> 4;
  int qt = blockIdx.x;
  int bh = blockIdx.y;
  int b = bh >> 4, h = bh & 15;
  size_t base = (size_t)b * SEQ * D_MODEL + h * HDIM;

  const u16* qrow = qb + base + (size_t)(qt*16 + r) * D_MODEL + kg*8;
  bf16x8 qf0 = *(const bf16x8*)(qrow);
  bf16x8 qf1 = *(const bf16x8*)(qrow + 32);

  f32x4 oacc[4];
  #pragma unroll
  for (int n = 0; n < 4; ++n) oacc[n] = f32x4{0.f, 0.f, 0.f, 0.f};
  float m_run[4] = {-1e30f, -1e30f, -1e30f, -1e30f};
  float l_run[4] = {0.f, 0.f, 0.f, 0.f};
  const int* mrow = mask + b * SEQ;

  for (int kt = 0; kt < SEQ/32; ++kt) {
    int key0 = kt * 32;
    const u16* kr0 = kb + base + (size_t)(key0 + r) * D_MODEL + kg*8;
    const u16* kr1 = kb + base + (size_t)(key0 + 16 + r) * D_MODEL + kg*8;
    bf16x8 kf00 = *(const bf16x8*)(kr0);
    bf16x8 kf01 = *(const bf16x8*)(kr0 + 32);
    bf16x8 kf10 = *(const bf16x8*)(kr1);
    bf16x8 kf11 = *(const bf16x8*)(kr1 + 32);
    f32x4 s0 = {0.f,0.f,0.f,0.f}, s1 = {0.f,0.f,0.f,0.f};
    s0 = MFMA_BF16(qf0, kf00, s0);
    s0 = MFMA_BF16(qf1, kf01, s0);
    s1 = MFMA_BF16(qf0, kf10, s1);
    s1 = MFMA_BF16(qf1, kf11, s1);

    int mk0 = mrow[key0 + r];
    int mk1 = mrow[key0 + 16 + r];
    float tm[4], p0a[4], p1a[4], ts[4];
    #pragma unroll
    for (int j = 0; j < 4; ++j) {
      float v0 = mk0 ? s0[j] * 0.125f : -1e9f;
      float v1 = mk1 ? s1[j] * 0.125f : -1e9f;
      s0[j] = v0; s1[j] = v1;
      tm[j] = fmaxf(v0, v1);
    }
    #pragma unroll
    for (int d = 1; d < 16; d <<= 1) {
      #pragma unroll
      for (int j = 0; j < 4; ++j) tm[j] = fmaxf(tm[j], __shfl_xor(tm[j], d));
    }
    #pragma unroll
    for (int j = 0; j < 4; ++j) {
      float mn = fmaxf(m_run[j], tm[j]);
      float al = __expf(m_run[j] - mn);
      p0a[j] = __expf(s0[j] - mn);
      p1a[j] = __expf(s1[j] - mn);
      ts[j] = p0a[j] + p1a[j];
      m_run[j] = mn;
      l_run[j] *= al;
      oacc[0][j] *= al; oacc[1][j] *= al; oacc[2][j] *= al; oacc[3][j] *= al;
    }
    #pragma unroll
    for (int d = 1; d < 16; d <<= 1) {
      #pragma unroll
      for (int j = 0; j < 4; ++j) ts[j] += __shfl_xor(ts[j], d);
    }
    #pragma unroll
    for (int j = 0; j < 4; ++j) l_run[j] += ts[j];

    // P (f32) -> LDS bf16, layout [qrow][key] stride 32
    #pragma unroll
    for (int j = 0; j < 4; ++j) {
      p_lds[(kg*4 + j)*32 + r]      = f2bf(p0a[j]);
      p_lds[(kg*4 + j)*32 + 16 + r] = f2bf(p1a[j]);
    }
    // V tile [32 keys][64 d] -> LDS transposed [d][key] stride 32
    #pragma unroll
    for (int i = 0; i < 4; ++i) {
      int c = lane + 64*i;        // 0..255
      int key = c >> 3;           // 0..31
      int d0 = (c & 7) * 8;       // 0..56
      bf16x8 vv = *(const bf16x8*)(vb + base + (size_t)(key0 + key) * D_MODEL + d0);
      u16* vp = (u16*)&vv;
      #pragma unroll
      for (int e = 0; e < 8; ++e) vt_lds[(d0 + e)*32 + key] = vp[e];
    }
    __syncthreads();
    bf16x8 pa = *(const bf16x8*)&p_lds[r*32 + kg*8];
    #pragma unroll
    for (int n = 0; n < 4; ++n) {
      bf16x8 vf = *(const bf16x8*)&vt_lds[(n*16 + r)*32 + kg*8];
      oacc[n] = MFMA_BF16(pa, vf, oacc[n]);
    }
    __syncthreads();
  }

  float rcp[4];
  #pragma unroll
  for (int j = 0; j < 4; ++j) rcp[j] = 1.0f / l_run[j];
  #pragma unroll
  for (int n = 0; n < 4; ++n) {
    #pragma unroll
    for (int j = 0; j < 4; ++j) {
      int q = qt*16 + kg*4 + j;
      int d = h*HDIM + n*16 + r;
      ob[(size_t)(b*SEQ + q) * D_MODEL + d] = f2bf(oacc[n][j] * rcp[j]);
    }
  }
}

// ---------------- launch ----------------
extern "C" void kernel_launch(void* const* d_in, const int* in_sizes, int n_in,
                              void* d_out, int out_size, void* d_ws, size_t ws_size,
                              hipStream_t stream) {
  const float* x   = (const float*)d_in[0];
  const int*  mask = (const int*)d_in[1];
  const float* Wq = (const float*)d_in[2];  const float* bq = (const float*)d_in[3];
  const float* Wk = (const float*)d_in[4];  const float* bk = (const float*)d_in[5];
  const float* Wv = (const float*)d_in[6];  const float* bv = (const float*)d_in[7];
  const float* Wo = (const float*)d_in[8];  const float* bo = (const float*)d_in[9];
  const float* W1 = (const float*)d_in[10]; const float* b1 = (const float*)d_in[11];
  const float* W2 = (const float*)d_in[12]; const float* b2 = (const float*)d_in[13];
  const float* g1 = (const float*)d_in[14]; const float* be1 = (const float*)d_in[15];
  const float* g2 = (const float*)d_in[16]; const float* be2 = (const float*)d_in[17];

  const size_t MB = 1u << 20;
  char* ws = (char*)d_ws;
  u16*  hln  = (u16*)(ws);              // 16MB (reused as h2 for LN2)
  u16*  qb   = (u16*)(ws + 16*MB);      // 16MB
  u16*  kb   = (u16*)(ws + 32*MB);      // 16MB
  u16*  vb   = (u16*)(ws + 48*MB);      // 16MB
  u16*  attn = (u16*)(ws + 64*MB);      // 16MB
  u16*  ff1  = (u16*)(ws + 16*MB);      // 64MB, reuses q/k/v/attn region
  float* x2  = (float*)(ws + 80*MB);    // 32MB
  u16*  WqT  = (u16*)(ws + 112*MB);     // 2MB each
  u16*  WkT  = (u16*)(ws + 114*MB);
  u16*  WvT  = (u16*)(ws + 116*MB);
  u16*  WoT  = (u16*)(ws + 118*MB);
  u16*  W1T  = (u16*)(ws + 120*MB);     // [4096,1024] 8MB
  u16*  W2T  = (u16*)(ws + 128*MB);     // [1024,4096] 8MB

  dim3 tb(256);
  wt_kernel<<<dim3(1024/32, 1024/32), tb, 0, stream>>>(Wq, WqT, 1024, 1024);
  wt_kernel<<<dim3(1024/32, 1024/32), tb, 0, stream>>>(Wk, WkT, 1024, 1024);
  wt_kernel<<<dim3(1024/32, 1024/32), tb, 0, stream>>>(Wv, WvT, 1024, 1024);
  wt_kernel<<<dim3(1024/32, 1024/32), tb, 0, stream>>>(Wo, WoT, 1024, 1024);
  wt_kernel<<<dim3(4096/32, 1024/32), tb, 0, stream>>>(W1, W1T, 1024, 4096);
  wt_kernel<<<dim3(1024/32, 4096/32), tb, 0, stream>>>(W2, W2T, 4096, 1024);

  ln_kernel<<<ROWS, tb, 0, stream>>>(x, g1, be1, hln);

  gemm_bt<0><<<dim3(1024/128, ROWS/128), tb, 0, stream>>>(hln, WqT, bq, nullptr, qb, ROWS, 1024, 1024);
  gemm_bt<0><<<dim3(1024/128, ROWS/128), tb, 0, stream>>>(hln, WkT, bk, nullptr, kb, ROWS, 1024, 1024);
  gemm_bt<0><<<dim3(1024/128, ROWS/128), tb, 0, stream>>>(hln, WvT, bv, nullptr, vb, ROWS, 1024, 1024);

  attn_kernel<<<dim3(SEQ/16, BATCH*NHEAD), dim3(64), 0, stream>>>(qb, kb, vb, mask, attn);

  gemm_bt<1><<<dim3(1024/128, ROWS/128), tb, 0, stream>>>(attn, WoT, bo, x, x2, ROWS, 1024, 1024);

  ln_kernel<<<ROWS, tb, 0, stream>>>(x2, g2, be2, hln);

  gemm_bt<2><<<dim3(4096/128, ROWS/128), tb, 0, stream>>>(hln, W1T, b1, nullptr, ff1, ROWS, 4096, 1024);

  gemm_bt<1><<<dim3(1024/128, ROWS/128), tb, 0, stream>>>(ff1, W2T, b2, x2, (float*)d_out, ROWS, 1024, 4096);
}

// Round 2
// 566.923 us; speedup vs baseline: 1.8593x; 1.8593x over previous
//
#include <hip/hip_runtime.h>
#include <stdint.h>

#define D_MODEL 1024
#define NHEAD   16
#define HDIM    64
#define FFDIM   4096
#define BATCH   4
#define SEQ     2048
#define ROWS    (BATCH*SEQ)   // 8192

typedef unsigned short u16;
typedef __bf16 bf16_t;
typedef bf16_t bf16x8 __attribute__((ext_vector_type(8)));
typedef float  f32x4  __attribute__((ext_vector_type(4)));

__device__ __forceinline__ u16 f2bf(float f) {
  union { float f; unsigned u; } v; v.f = f;
  unsigned r = v.u + 0x7fffu + ((v.u >> 16) & 1u);
  return (u16)(r >> 16);
}

__device__ __forceinline__ void gl2lds16(const void* g, void* l) {
  __builtin_amdgcn_global_load_lds((const __attribute__((address_space(1))) void*)g,
                                   (__attribute__((address_space(3))) void*)l, 16, 0, 0);
}

#define MFMA_BF16(a, b, c) __builtin_amdgcn_mfma_f32_16x16x32_bf16((a), (b), (c), 0, 0, 0)

// ---------------- LayerNorm (fp32 in -> bf16 out) ----------------
__global__ __launch_bounds__(256) void ln_kernel(const float* __restrict__ x,
                                                 const float* __restrict__ g,
                                                 const float* __restrict__ be,
                                                 u16* __restrict__ out) {
  __shared__ float red[10];
  int row = blockIdx.x;
  int t = threadIdx.x;
  const float* xr = x + (size_t)row * D_MODEL;
  float4 xv = ((const float4*)xr)[t];
  float s  = xv.x + xv.y + xv.z + xv.w;
  float s2 = xv.x*xv.x + xv.y*xv.y + xv.z*xv.z + xv.w*xv.w;
  for (int d = 32; d > 0; d >>= 1) { s += __shfl_down(s, d); s2 += __shfl_down(s2, d); }
  int wid = t >> 6;
  if ((t & 63) == 0) { red[wid*2] = s; red[wid*2+1] = s2; }
  __syncthreads();
  if (t == 0) {
    float a = 0.f, b2 = 0.f;
    for (int i = 0; i < 4; ++i) { a += red[i*2]; b2 += red[i*2+1]; }
    red[8] = a; red[9] = b2;
  }
  __syncthreads();
  float mu  = red[8] * (1.0f / D_MODEL);
  float var = red[9] * (1.0f / D_MODEL) - mu*mu;
  float rstd = rsqrtf(var + 1e-12f);
  float4 gv = ((const float4*)g)[t];
  float4 bv = ((const float4*)be)[t];
  unsigned long long o =
      (unsigned long long)f2bf((xv.x - mu) * rstd * gv.x + bv.x)
    | ((unsigned long long)f2bf((xv.y - mu) * rstd * gv.y + bv.y) << 16)
    | ((unsigned long long)f2bf((xv.z - mu) * rstd * gv.z + bv.z) << 32)
    | ((unsigned long long)f2bf((xv.w - mu) * rstd * gv.w + bv.w) << 48);
  ((unsigned long long*)out)[(size_t)row * (D_MODEL/4) + t] = o;
}

// ---------------- Weight transpose fp32 [K,N] -> bf16 [N,K] ----------------
__global__ __launch_bounds__(256) void wt_kernel(const float* __restrict__ W,
                                                 u16* __restrict__ Wt, int K, int N) {
  __shared__ float tile[32][33];
  int n0 = blockIdx.x * 32, k0 = blockIdx.y * 32;
  int tx = threadIdx.x & 31, ty = threadIdx.x >> 5;   // ty: 0..7
  #pragma unroll
  for (int i = 0; i < 4; ++i) {
    int k = ty + i*8;
    tile[k][tx] = W[(size_t)(k0 + k) * N + n0 + tx];
  }
  __syncthreads();
  #pragma unroll
  for (int i = 0; i < 4; ++i) {
    int n = ty + i*8;
    Wt[(size_t)(n0 + n) * K + k0 + tx] = f2bf(tile[tx][n]);
  }
}

// ---------------- V transpose: [b,key,h,d] bf16 -> [b,h,d,key] bf16 --------
__global__ __launch_bounds__(256) void vtrans_kernel(const u16* __restrict__ vb,
                                                     u16* __restrict__ vt) {
  __shared__ __align__(16) u16 tile[64][80];
  int kb = blockIdx.x * 64;       // key block
  int bh = blockIdx.y;            // b*16+h
  int b = bh >> 4, h = bh & 15;
  int t = threadIdx.x;
  int key = t >> 2, dq = (t & 3) * 16;
  const u16* src = vb + (size_t)b*SEQ*D_MODEL + (size_t)(kb+key)*D_MODEL + h*HDIM + dq;
  *(bf16x8*)&tile[key][dq]     = *(const bf16x8*)(src);
  *(bf16x8*)&tile[key][dq + 8] = *(const bf16x8*)(src + 8);
  __syncthreads();
  int w = t >> 6, lane = t & 63;
  int kq = w * 16;
  u16 vals[16];
  #pragma unroll
  for (int e = 0; e < 16; ++e) vals[e] = tile[kq + e][lane];
  u16* dst = vt + (size_t)bh * HDIM * SEQ + (size_t)lane * SEQ + kb + kq;
  *(bf16x8*)dst       = *(const bf16x8*)&vals[0];
  *(bf16x8*)(dst + 8) = *(const bf16x8*)&vals[8];
}

// ---------------- GEMM: C[M,N] = A[M,K] @ Bt[N,K]^T (+bias, epilogue) -------
__device__ __forceinline__ float gelu_f(float v) {
  return 0.5f * v * (1.0f + erff(v * 0.70710678118654752f));
}

template<int EPI>
__global__ __launch_bounds__(256) void gemm_bt(const u16* __restrict__ A,
                                               const u16* __restrict__ Bt,
                                               const float* __restrict__ bias,
                                               const float* __restrict__ resid,
                                               void* __restrict__ outp,
                                               int M, int N, int K) {
  __shared__ __align__(16) u16 sA[128*32];
  __shared__ __align__(16) u16 sB[128*32];
  int tid = threadIdx.x;
  int lane = tid & 63, w = tid >> 6;
  int r = lane & 15, kg = lane >> 4;
  int wr = w >> 1, wc = w & 1;
  int bm = blockIdx.y, bn = blockIdx.x;

  f32x4 acc[4][4];
  #pragma unroll
  for (int m = 0; m < 4; ++m)
    #pragma unroll
    for (int n = 0; n < 4; ++n) acc[m][n] = f32x4{0.f, 0.f, 0.f, 0.f};

  int cr0 = w*16 + (lane >> 2), cr1 = (w+4)*16 + (lane >> 2);
  int ccol = (lane & 3) * 8;
  const u16* Ag0 = A  + (size_t)(bm*128 + cr0) * K + ccol;
  const u16* Ag1 = A  + (size_t)(bm*128 + cr1) * K + ccol;
  const u16* Bg0 = Bt + (size_t)(bn*128 + cr0) * K + ccol;
  const u16* Bg1 = Bt + (size_t)(bn*128 + cr1) * K + ccol;
  u16* lA0 = sA + w*512 + lane*8;
  u16* lA1 = sA + (w+4)*512 + lane*8;
  u16* lB0 = sB + w*512 + lane*8;
  u16* lB1 = sB + (w+4)*512 + lane*8;

  for (int k0 = 0; k0 < K; k0 += 32) {
    gl2lds16(Ag0 + k0, lA0);
    gl2lds16(Ag1 + k0, lA1);
    gl2lds16(Bg0 + k0, lB0);
    gl2lds16(Bg1 + k0, lB1);
    __syncthreads();
    bf16x8 af[4], bfr[4];
    #pragma unroll
    for (int m = 0; m < 4; ++m) af[m]  = *(const bf16x8*)&sA[(wr*64 + m*16 + r)*32 + kg*8];
    #pragma unroll
    for (int n = 0; n < 4; ++n) bfr[n] = *(const bf16x8*)&sB[(wc*64 + n*16 + r)*32 + kg*8];
    #pragma unroll
    for (int m = 0; m < 4; ++m)
      #pragma unroll
      for (int n = 0; n < 4; ++n)
        acc[m][n] = MFMA_BF16(af[m], bfr[n], acc[m][n]);
    __syncthreads();
  }

  int orow = bm*128 + wr*64, ocol = bn*128 + wc*64;
  #pragma unroll
  for (int m = 0; m < 4; ++m) {
    #pragma unroll
    for (int n = 0; n < 4; ++n) {
      #pragma unroll
      for (int j = 0; j < 4; ++j) {
        int rr = orow + m*16 + kg*4 + j;
        int cc = ocol + n*16 + r;
        size_t idx = (size_t)rr * N + cc;
        float v = acc[m][n][j] + bias[cc];
        if (EPI == 0)       ((u16*)outp)[idx]   = f2bf(v);
        else if (EPI == 1)  ((float*)outp)[idx] = resid[idx] + v;
        else                ((u16*)outp)[idx]   = f2bf(gelu_f(v));
      }
    }
  }
}

// ---------------- Flash attention: 4 waves/block, QBLK=64, KVBLK=64 --------
// Softmax in exp2 domain; defer-max (THR=8 ln-domain) gates the shfl-max
// tree + rescale behind a wave-uniform __any(); row-sum accumulated
// lane-locally, reduced once after the loop.
__global__ __launch_bounds__(256) void attn_kernel(const u16* __restrict__ qb,
                                                   const u16* __restrict__ kb,
                                                   const u16* __restrict__ vt,
                                                   const int* __restrict__ mask,
                                                   u16* __restrict__ ob) {
  __shared__ __align__(16) u16 sK[2][64*64];
  __shared__ __align__(16) u16 sV[2][64*64];
  __shared__ __align__(16) bf16_t sP[4][16*64];
  const float SC   = 0.18033688011112042f;   // 0.125 * log2(e)
  const float THR2 = 11.541560327111708f;    // 8 * log2(e)
  int tid = threadIdx.x;
  int lane = tid & 63, w = tid >> 6;
  int r = lane & 15, kg = lane >> 4;
  int r7 = r & 7;
  int qt = blockIdx.x;
  int bh = blockIdx.y;
  int b = bh >> 4, h = bh & 15;
  size_t qkbase = (size_t)b * SEQ * D_MODEL + (size_t)h * HDIM;
  const u16* vtb = vt + (size_t)bh * HDIM * SEQ;
  const int* mrow = mask + b * SEQ;

  const u16* qrow = qb + qkbase + (size_t)(qt*64 + w*16 + r) * D_MODEL + kg*8;
  bf16x8 qf[2];
  qf[0] = *(const bf16x8*)(qrow);
  qf[1] = *(const bf16x8*)(qrow + 32);

  f32x4 oacc[4];
  #pragma unroll
  for (int n = 0; n < 4; ++n) oacc[n] = f32x4{0.f, 0.f, 0.f, 0.f};
  float m_run[4] = {-1e30f, -1e30f, -1e30f, -1e30f};
  float lsum[4]  = {0.f, 0.f, 0.f, 0.f};

  const int NT = SEQ / 64;

  auto stage = [&](int buf, int kt) {
    int key0 = kt * 64;
    #pragma unroll
    for (int c = 0; c < 2; ++c) {
      int ch  = w*64 + lane + c*256;      // 0..511 chunk id
      int row = ch >> 3, g = ch & 7;
      int col = ((g ^ (row & 7)) * 8);
      gl2lds16(kb  + qkbase + (size_t)(key0 + row) * D_MODEL + col, &sK[buf][ch*8]);
      gl2lds16(vtb + (size_t)row * SEQ + key0 + col,                &sV[buf][ch*8]);
    }
  };

  stage(0, 0);
  #pragma unroll 2
  for (int kt = 0; kt < NT; ++kt) {
    int cur = kt & 1;
    int key0 = kt * 64;
    if (kt + 1 < NT) {
      stage(cur ^ 1, kt + 1);
      asm volatile("s_waitcnt vmcnt(4)" ::: "memory");
    } else {
      asm volatile("s_waitcnt vmcnt(0)" ::: "memory");
    }
    __builtin_amdgcn_s_barrier();

    const u16* Kt = sK[cur];
    const u16* Vt = sV[cur];

    // ---- QK^T: 16q x 64k, C-frag: row q=kg*4+j, col key=n*16+r ----
    f32x4 s[4];
    #pragma unroll
    for (int n = 0; n < 4; ++n) s[n] = f32x4{0.f, 0.f, 0.f, 0.f};
    #pragma unroll
    for (int c = 0; c < 2; ++c) {
      #pragma unroll
      for (int n = 0; n < 4; ++n) {
        bf16x8 kf = *(const bf16x8*)&Kt[(n*16 + r)*64 + (((c*4 + kg) ^ r7) * 8)];
        s[n] = MFMA_BF16(qf[c], kf, s[n]);
      }
    }

    // ---- mask + scale into exp2 domain; lane-local max ----
    int mk[4];
    #pragma unroll
    for (int n = 0; n < 4; ++n) mk[n] = mrow[key0 + n*16 + r];
    float tm[4];
    #pragma unroll
    for (int n = 0; n < 4; ++n) {
      #pragma unroll
      for (int j = 0; j < 4; ++j) {
        float v = mk[n] ? s[n][j] * SC : -1e9f;
        s[n][j] = v;
        tm[j] = (n == 0) ? v : fmaxf(tm[j], v);
      }
    }
    // ---- defer-max: rescale only when some lane's local max breaches ----
    bool grow = (tm[0] > m_run[0] + THR2) | (tm[1] > m_run[1] + THR2) |
                (tm[2] > m_run[2] + THR2) | (tm[3] > m_run[3] + THR2);
    if (__any(grow)) {
      #pragma unroll
      for (int d = 1; d < 16; d <<= 1) {
        #pragma unroll
        for (int j = 0; j < 4; ++j) tm[j] = fmaxf(tm[j], __shfl_xor(tm[j], d));
      }
      #pragma unroll
      for (int j = 0; j < 4; ++j) {
        float mn = fmaxf(m_run[j], tm[j]);
        float al = exp2f(m_run[j] - mn);
        m_run[j] = mn;
        lsum[j] *= al;
        oacc[0][j] *= al; oacc[1][j] *= al; oacc[2][j] *= al; oacc[3][j] *= al;
      }
    }
    // ---- P = exp2(s - m); lane-local row-sum; store to per-wave LDS ----
    bf16_t* pw = sP[w];
    #pragma unroll
    for (int n = 0; n < 4; ++n) {
      int cg = n*2 + (r >> 3);
      #pragma unroll
      for (int j = 0; j < 4; ++j) {
        float p = exp2f(s[n][j] - m_run[j]);
        lsum[j] += p;
        int row = kg*4 + j;
        pw[row*64 + ((cg ^ (row & 7)) * 8) + r7] = (bf16_t)p;
      }
    }
    bf16x8 pa[2];
    #pragma unroll
    for (int c = 0; c < 2; ++c)
      pa[c] = *(const bf16x8*)&sP[w][r*64 + (((c*4 + kg) ^ r7) * 8)];
    #pragma unroll
    for (int n = 0; n < 4; ++n) {
      #pragma unroll
      for (int c = 0; c < 2; ++c) {
        bf16x8 vf = *(const bf16x8*)&Vt[(n*16 + r)*64 + (((c*4 + kg) ^ r7) * 8)];
        oacc[n] = MFMA_BF16(pa[c], vf, oacc[n]);
      }
    }
    __builtin_amdgcn_s_barrier();
  }

  // final row-sum reduction across the 16 r-lanes (rows are per-kg-group)
  #pragma unroll
  for (int d = 1; d < 16; d <<= 1) {
    #pragma unroll
    for (int j = 0; j < 4; ++j) lsum[j] += __shfl_xor(lsum[j], d);
  }
  float rcp[4];
  #pragma unroll
  for (int j = 0; j < 4; ++j) rcp[j] = 1.0f / lsum[j];
  #pragma unroll
  for (int n = 0; n < 4; ++n) {
    #pragma unroll
    for (int j = 0; j < 4; ++j) {
      int q = qt*64 + w*16 + kg*4 + j;
      int d = h*HDIM + n*16 + r;
      ob[(size_t)(b*SEQ + q) * D_MODEL + d] = f2bf(oacc[n][j] * rcp[j]);
    }
  }
}

// ---------------- launch ----------------
extern "C" void kernel_launch(void* const* d_in, const int* in_sizes, int n_in,
                              void* d_out, int out_size, void* d_ws, size_t ws_size,
                              hipStream_t stream) {
  const float* x   = (const float*)d_in[0];
  const int*  mask = (const int*)d_in[1];
  const float* Wq = (const float*)d_in[2];  const float* bq = (const float*)d_in[3];
  const float* Wk = (const float*)d_in[4];  const float* bk = (const float*)d_in[5];
  const float* Wv = (const float*)d_in[6];  const float* bv = (const float*)d_in[7];
  const float* Wo = (const float*)d_in[8];  const float* bo = (const float*)d_in[9];
  const float* W1 = (const float*)d_in[10]; const float* b1 = (const float*)d_in[11];
  const float* W2 = (const float*)d_in[12]; const float* b2 = (const float*)d_in[13];
  const float* g1 = (const float*)d_in[14]; const float* be1 = (const float*)d_in[15];
  const float* g2 = (const float*)d_in[16]; const float* be2 = (const float*)d_in[17];

  const size_t MB = 1u << 20;
  char* ws = (char*)d_ws;
  u16*  hln  = (u16*)(ws);              // 16MB  (LN1 out; later reused: vt, then LN2 out)
  u16*  vt   = (u16*)(ws);              // 16MB  V^T [b,h,d,key] — overwrites hln after QKV
  u16*  qb   = (u16*)(ws + 16*MB);      // 16MB
  u16*  kb   = (u16*)(ws + 32*MB);      // 16MB
  u16*  vb   = (u16*)(ws + 48*MB);      // 16MB
  u16*  attn = (u16*)(ws + 64*MB);      // 16MB
  u16*  ff1  = (u16*)(ws + 16*MB);      // 64MB, reuses q/k/v/attn region
  float* x2  = (float*)(ws + 80*MB);    // 32MB
  u16*  WqT  = (u16*)(ws + 112*MB);
  u16*  WkT  = (u16*)(ws + 114*MB);
  u16*  WvT  = (u16*)(ws + 116*MB);
  u16*  WoT  = (u16*)(ws + 118*MB);
  u16*  W1T  = (u16*)(ws + 120*MB);     // [4096,1024] 8MB
  u16*  W2T  = (u16*)(ws + 128*MB);     // [1024,4096] 8MB

  dim3 tb(256);
  wt_kernel<<<dim3(1024/32, 1024/32), tb, 0, stream>>>(Wq, WqT, 1024, 1024);
  wt_kernel<<<dim3(1024/32, 1024/32), tb, 0, stream>>>(Wk, WkT, 1024, 1024);
  wt_kernel<<<dim3(1024/32, 1024/32), tb, 0, stream>>>(Wv, WvT, 1024, 1024);
  wt_kernel<<<dim3(1024/32, 1024/32), tb, 0, stream>>>(Wo, WoT, 1024, 1024);
  wt_kernel<<<dim3(4096/32, 1024/32), tb, 0, stream>>>(W1, W1T, 1024, 4096);
  wt_kernel<<<dim3(1024/32, 4096/32), tb, 0, stream>>>(W2, W2T, 4096, 1024);

  ln_kernel<<<ROWS, tb, 0, stream>>>(x, g1, be1, hln);

  gemm_bt<0><<<dim3(1024/128, ROWS/128), tb, 0, stream>>>(hln, WqT, bq, nullptr, qb, ROWS, 1024, 1024);
  gemm_bt<0><<<dim3(1024/128, ROWS/128), tb, 0, stream>>>(hln, WkT, bk, nullptr, kb, ROWS, 1024, 1024);
  gemm_bt<0><<<dim3(1024/128, ROWS/128), tb, 0, stream>>>(hln, WvT, bv, nullptr, vb, ROWS, 1024, 1024);

  vtrans_kernel<<<dim3(SEQ/64, BATCH*NHEAD), tb, 0, stream>>>(vb, vt);

  attn_kernel<<<dim3(SEQ/64, BATCH*NHEAD), tb, 0, stream>>>(qb, kb, vt, mask, attn);

  gemm_bt<1><<<dim3(1024/128, ROWS/128), tb, 0, stream>>>(attn, WoT, bo, x, x2, ROWS, 1024, 1024);

  ln_kernel<<<ROWS, tb, 0, stream>>>(x2, g2, be2, hln);

  gemm_bt<2><<<dim3(4096/128, ROWS/128), tb, 0, stream>>>(hln, W1T, b1, nullptr, ff1, ROWS, 4096, 1024);

  gemm_bt<1><<<dim3(1024/128, ROWS/128), tb, 0, stream>>>(ff1, W2T, b2, x2, (float*)d_out, ROWS, 1024, 4096);
}

// Round 3
// 489.996 us; speedup vs baseline: 2.1512x; 1.1570x over previous
//
#include <hip/hip_runtime.h>
#include <stdint.h>

#define D_MODEL 1024
#define NHEAD   16
#define HDIM    64
#define FFDIM   4096
#define BATCH   4
#define SEQ     2048
#define ROWS    (BATCH*SEQ)   // 8192

typedef unsigned short u16;
typedef __bf16 bf16_t;
typedef bf16_t bf16x8 __attribute__((ext_vector_type(8)));
typedef float  f32x4  __attribute__((ext_vector_type(4)));

__device__ __forceinline__ u16 f2bf(float f) {
  union { float f; unsigned u; } v; v.f = f;
  unsigned r = v.u + 0x7fffu + ((v.u >> 16) & 1u);
  return (u16)(r >> 16);
}

__device__ __forceinline__ void gl2lds16(const void* g, void* l) {
  __builtin_amdgcn_global_load_lds((const __attribute__((address_space(1))) void*)g,
                                   (__attribute__((address_space(3))) void*)l, 16, 0, 0);
}

#define MFMA_BF16(a, b, c) __builtin_amdgcn_mfma_f32_16x16x32_bf16((a), (b), (c), 0, 0, 0)

// ---------------- LayerNorm (fp32 in -> bf16 out) ----------------
__global__ __launch_bounds__(256) void ln_kernel(const float* __restrict__ x,
                                                 const float* __restrict__ g,
                                                 const float* __restrict__ be,
                                                 u16* __restrict__ out) {
  __shared__ float red[10];
  int row = blockIdx.x;
  int t = threadIdx.x;
  const float* xr = x + (size_t)row * D_MODEL;
  float4 xv = ((const float4*)xr)[t];
  float s  = xv.x + xv.y + xv.z + xv.w;
  float s2 = xv.x*xv.x + xv.y*xv.y + xv.z*xv.z + xv.w*xv.w;
  for (int d = 32; d > 0; d >>= 1) { s += __shfl_down(s, d); s2 += __shfl_down(s2, d); }
  int wid = t >> 6;
  if ((t & 63) == 0) { red[wid*2] = s; red[wid*2+1] = s2; }
  __syncthreads();
  if (t == 0) {
    float a = 0.f, b2 = 0.f;
    for (int i = 0; i < 4; ++i) { a += red[i*2]; b2 += red[i*2+1]; }
    red[8] = a; red[9] = b2;
  }
  __syncthreads();
  float mu  = red[8] * (1.0f / D_MODEL);
  float var = red[9] * (1.0f / D_MODEL) - mu*mu;
  float rstd = rsqrtf(var + 1e-12f);
  float4 gv = ((const float4*)g)[t];
  float4 bv = ((const float4*)be)[t];
  unsigned long long o =
      (unsigned long long)f2bf((xv.x - mu) * rstd * gv.x + bv.x)
    | ((unsigned long long)f2bf((xv.y - mu) * rstd * gv.y + bv.y) << 16)
    | ((unsigned long long)f2bf((xv.z - mu) * rstd * gv.z + bv.z) << 32)
    | ((unsigned long long)f2bf((xv.w - mu) * rstd * gv.w + bv.w) << 48);
  ((unsigned long long*)out)[(size_t)row * (D_MODEL/4) + t] = o;
}

// ---------------- Weight transpose fp32 [K,N] -> bf16 [N,K] ----------------
__global__ __launch_bounds__(256) void wt_kernel(const float* __restrict__ W,
                                                 u16* __restrict__ Wt, int K, int N) {
  __shared__ float tile[32][33];
  int n0 = blockIdx.x * 32, k0 = blockIdx.y * 32;
  int tx = threadIdx.x & 31, ty = threadIdx.x >> 5;   // ty: 0..7
  #pragma unroll
  for (int i = 0; i < 4; ++i) {
    int k = ty + i*8;
    tile[k][tx] = W[(size_t)(k0 + k) * N + n0 + tx];
  }
  __syncthreads();
  #pragma unroll
  for (int i = 0; i < 4; ++i) {
    int n = ty + i*8;
    Wt[(size_t)(n0 + n) * K + k0 + tx] = f2bf(tile[tx][n]);
  }
}

// ---------------- V transpose: [b,key,h,d] bf16 -> [b,h,d,key] bf16 --------
__global__ __launch_bounds__(256) void vtrans_kernel(const u16* __restrict__ vb,
                                                     u16* __restrict__ vt) {
  __shared__ __align__(16) u16 tile[64][80];
  int kb = blockIdx.x * 64;       // key block
  int bh = blockIdx.y;            // b*16+h
  int b = bh >> 4, h = bh & 15;
  int t = threadIdx.x;
  int key = t >> 2, dq = (t & 3) * 16;
  const u16* src = vb + (size_t)b*SEQ*D_MODEL + (size_t)(kb+key)*D_MODEL + h*HDIM + dq;
  *(bf16x8*)&tile[key][dq]     = *(const bf16x8*)(src);
  *(bf16x8*)&tile[key][dq + 8] = *(const bf16x8*)(src + 8);
  __syncthreads();
  int w = t >> 6, lane = t & 63;
  int kq = w * 16;
  u16 vals[16];
  #pragma unroll
  for (int e = 0; e < 16; ++e) vals[e] = tile[kq + e][lane];
  u16* dst = vt + (size_t)bh * HDIM * SEQ + (size_t)lane * SEQ + kb + kq;
  *(bf16x8*)dst       = *(const bf16x8*)&vals[0];
  *(bf16x8*)(dst + 8) = *(const bf16x8*)&vals[8];
}

// ---------------- GEMM 128x256, BK=64, tri-buffered 8-phase-style ----------
// C[M,N] = A[M,K] @ Bt[N,K]^T (+bias, epilogue)
// EPI 0: bf16 out = C + bias
// EPI 1: f32  out = resid + C + bias
// EPI 2: bf16 out = gelu(C + bias)
__device__ __forceinline__ float gelu_f(float v) {
  return 0.5f * v * (1.0f + erff(v * 0.70710678118654752f));
}

template<int EPI>
__global__ __launch_bounds__(512, 2) void gemm256(const u16* __restrict__ A,
                                                  const u16* __restrict__ Bt,
                                                  const float* __restrict__ bias,
                                                  const float* __restrict__ resid,
                                                  void* __restrict__ outp,
                                                  int M, int N, int K) {
  __shared__ __align__(16) u16 sA[3][128*64];   // 48 KiB
  __shared__ __align__(16) u16 sB[3][256*64];   // 96 KiB
  const int tid = threadIdx.x;
  const int lane = tid & 63, w = tid >> 6;
  const int r = lane & 15, kg = lane >> 4, r7 = r & 7;
  const int wr = w >> 2, wc = w & 3;

  // XCD-aware bijective swizzle (all launches have nwg % 8 == 0)
  const int gx = gridDim.x;
  const int nwg = gx * gridDim.y;
  const int orig = blockIdx.y * gx + blockIdx.x;
  const int lid = (orig & 7) * (nwg >> 3) + (orig >> 3);
  const int bm = lid / gx, bn = lid % gx;

  const int NT = K >> 6;

  // per-unit stage offsets: slot = u*512 + tid; row = slot>>3, group g = slot&7
  // global source column pre-swizzled: col = (g ^ (row&7))*8  (T2, both-sides)
  size_t offA[2], offB[4];
  #pragma unroll
  for (int u = 0; u < 2; ++u) {
    int slot = u*512 + tid;
    int row = slot >> 3, g = slot & 7;
    offA[u] = (size_t)(bm*128 + row) * K + ((g ^ (row & 7)) * 8);
  }
  #pragma unroll
  for (int u = 0; u < 4; ++u) {
    int slot = u*512 + tid;
    int row = slot >> 3, g = slot & 7;
    offB[u] = (size_t)(bn*256 + row) * K + ((g ^ (row & 7)) * 8);
  }

  f32x4 acc[4][4];
  #pragma unroll
  for (int m = 0; m < 4; ++m)
    #pragma unroll
    for (int n = 0; n < 4; ++n) acc[m][n] = f32x4{0.f, 0.f, 0.f, 0.f};

  float bv4[4];
  #pragma unroll
  for (int n = 0; n < 4; ++n) bv4[n] = bias[bn*256 + wc*64 + n*16 + r];

  // ---- prologue: stage K-tiles 0 and 1 ----
  #pragma unroll
  for (int u = 0; u < 2; ++u) gl2lds16(A  + offA[u],      &sA[0][(u*512+tid)*8]);
  #pragma unroll
  for (int u = 0; u < 4; ++u) gl2lds16(Bt + offB[u],      &sB[0][(u*512+tid)*8]);
  #pragma unroll
  for (int u = 0; u < 2; ++u) gl2lds16(A  + offA[u] + 64, &sA[1][(u*512+tid)*8]);
  #pragma unroll
  for (int u = 0; u < 4; ++u) gl2lds16(Bt + offB[u] + 64, &sB[1][(u*512+tid)*8]);
  asm volatile("s_waitcnt vmcnt(6)" ::: "memory");
  __builtin_amdgcn_s_barrier();

  int buf = 0;
  for (int t = 0; t < NT; ++t) {
    const bool pre = (t + 2 < NT);
    int nb = buf + 2; if (nb >= 3) nb -= 3;
    const size_t koff = (size_t)(t + 2) * 64;

    // ======== phase 0 (k-slice 0) ========
    bf16x8 af0[4], bf0[4];
    #pragma unroll
    for (int m = 0; m < 4; ++m)
      af0[m] = *(const bf16x8*)&sA[buf][(wr*64 + m*16 + r)*64 + ((kg ^ r7) * 8)];
    #pragma unroll
    for (int n = 0; n < 4; ++n)
      bf0[n] = *(const bf16x8*)&sB[buf][(wc*64 + n*16 + r)*64 + ((kg ^ r7) * 8)];
    if (pre) {
      gl2lds16(A  + offA[0] + koff, &sA[nb][(0*512+tid)*8]);
      gl2lds16(A  + offA[1] + koff, &sA[nb][(1*512+tid)*8]);
      gl2lds16(Bt + offB[0] + koff, &sB[nb][(0*512+tid)*8]);
    }
    __builtin_amdgcn_s_barrier();
    asm volatile("s_waitcnt lgkmcnt(0)" ::: "memory");
    __builtin_amdgcn_s_setprio(1);
    #pragma unroll
    for (int m = 0; m < 4; ++m)
      #pragma unroll
      for (int n = 0; n < 4; ++n)
        acc[m][n] = MFMA_BF16(af0[m], bf0[n], acc[m][n]);
    __builtin_amdgcn_s_setprio(0);
    __builtin_amdgcn_s_barrier();

    // ======== phase 1 (k-slice 1) ========
    bf16x8 af1[4], bf1[4];
    #pragma unroll
    for (int m = 0; m < 4; ++m)
      af1[m] = *(const bf16x8*)&sA[buf][(wr*64 + m*16 + r)*64 + (((4 + kg) ^ r7) * 8)];
    #pragma unroll
    for (int n = 0; n < 4; ++n)
      bf1[n] = *(const bf16x8*)&sB[buf][(wc*64 + n*16 + r)*64 + (((4 + kg) ^ r7) * 8)];
    if (pre) {
      gl2lds16(Bt + offB[1] + koff, &sB[nb][(1*512+tid)*8]);
      gl2lds16(Bt + offB[2] + koff, &sB[nb][(2*512+tid)*8]);
      gl2lds16(Bt + offB[3] + koff, &sB[nb][(3*512+tid)*8]);
    }
    __builtin_amdgcn_s_barrier();
    asm volatile("s_waitcnt lgkmcnt(0)" ::: "memory");
    __builtin_amdgcn_s_setprio(1);
    #pragma unroll
    for (int m = 0; m < 4; ++m)
      #pragma unroll
      for (int n = 0; n < 4; ++n)
        acc[m][n] = MFMA_BF16(af1[m], bf1[n], acc[m][n]);
    __builtin_amdgcn_s_setprio(0);
    if (pre) asm volatile("s_waitcnt vmcnt(6)" ::: "memory");
    else     asm volatile("s_waitcnt vmcnt(0)" ::: "memory");
    __builtin_amdgcn_s_barrier();
    buf += 1; if (buf >= 3) buf -= 3;
  }

  // ---- epilogue ----
  const int orow = bm*128 + wr*64, ocol = bn*256 + wc*64;
  #pragma unroll
  for (int m = 0; m < 4; ++m) {
    #pragma unroll
    for (int n = 0; n < 4; ++n) {
      #pragma unroll
      for (int j = 0; j < 4; ++j) {
        int rr = orow + m*16 + kg*4 + j;
        int cc = ocol + n*16 + r;
        size_t idx = (size_t)rr * N + cc;
        float v = acc[m][n][j] + bv4[n];
        if (EPI == 0)       ((u16*)outp)[idx]   = f2bf(v);
        else if (EPI == 1)  ((float*)outp)[idx] = resid[idx] + v;
        else                ((u16*)outp)[idx]   = f2bf(gelu_f(v));
      }
    }
  }
}

// ---------------- Flash attention: 4 waves/block, QBLK=64, KVBLK=64 --------
__global__ __launch_bounds__(256) void attn_kernel(const u16* __restrict__ qb,
                                                   const u16* __restrict__ kb,
                                                   const u16* __restrict__ vt,
                                                   const int* __restrict__ mask,
                                                   u16* __restrict__ ob) {
  __shared__ __align__(16) u16 sK[2][64*64];
  __shared__ __align__(16) u16 sV[2][64*64];
  __shared__ __align__(16) bf16_t sP[4][16*64];
  const float SC   = 0.18033688011112042f;   // 0.125 * log2(e)
  const float THR2 = 11.541560327111708f;    // 8 * log2(e)
  int tid = threadIdx.x;
  int lane = tid & 63, w = tid >> 6;
  int r = lane & 15, kg = lane >> 4;
  int r7 = r & 7;
  int qt = blockIdx.x;
  int bh = blockIdx.y;
  int b = bh >> 4, h = bh & 15;
  size_t qkbase = (size_t)b * SEQ * D_MODEL + (size_t)h * HDIM;
  const u16* vtb = vt + (size_t)bh * HDIM * SEQ;
  const int* mrow = mask + b * SEQ;

  const u16* qrow = qb + qkbase + (size_t)(qt*64 + w*16 + r) * D_MODEL + kg*8;
  bf16x8 qf[2];
  qf[0] = *(const bf16x8*)(qrow);
  qf[1] = *(const bf16x8*)(qrow + 32);

  f32x4 oacc[4];
  #pragma unroll
  for (int n = 0; n < 4; ++n) oacc[n] = f32x4{0.f, 0.f, 0.f, 0.f};
  float m_run[4] = {-1e30f, -1e30f, -1e30f, -1e30f};
  float lsum[4]  = {0.f, 0.f, 0.f, 0.f};

  const int NT = SEQ / 64;

  auto stage = [&](int buf, int kt) {
    int key0 = kt * 64;
    #pragma unroll
    for (int c = 0; c < 2; ++c) {
      int ch  = w*64 + lane + c*256;      // 0..511 chunk id
      int row = ch >> 3, g = ch & 7;
      int col = ((g ^ (row & 7)) * 8);
      gl2lds16(kb  + qkbase + (size_t)(key0 + row) * D_MODEL + col, &sK[buf][ch*8]);
      gl2lds16(vtb + (size_t)row * SEQ + key0 + col,                &sV[buf][ch*8]);
    }
  };

  stage(0, 0);
  #pragma unroll 2
  for (int kt = 0; kt < NT; ++kt) {
    int cur = kt & 1;
    int key0 = kt * 64;
    if (kt + 1 < NT) {
      stage(cur ^ 1, kt + 1);
      asm volatile("s_waitcnt vmcnt(4)" ::: "memory");
    } else {
      asm volatile("s_waitcnt vmcnt(0)" ::: "memory");
    }
    __builtin_amdgcn_s_barrier();

    const u16* Kt = sK[cur];
    const u16* Vt = sV[cur];

    f32x4 s[4];
    #pragma unroll
    for (int n = 0; n < 4; ++n) s[n] = f32x4{0.f, 0.f, 0.f, 0.f};
    #pragma unroll
    for (int c = 0; c < 2; ++c) {
      #pragma unroll
      for (int n = 0; n < 4; ++n) {
        bf16x8 kf = *(const bf16x8*)&Kt[(n*16 + r)*64 + (((c*4 + kg) ^ r7) * 8)];
        s[n] = MFMA_BF16(qf[c], kf, s[n]);
      }
    }

    int mk[4];
    #pragma unroll
    for (int n = 0; n < 4; ++n) mk[n] = mrow[key0 + n*16 + r];
    float tm[4];
    #pragma unroll
    for (int n = 0; n < 4; ++n) {
      #pragma unroll
      for (int j = 0; j < 4; ++j) {
        float v = mk[n] ? s[n][j] * SC : -1e9f;
        s[n][j] = v;
        tm[j] = (n == 0) ? v : fmaxf(tm[j], v);
      }
    }
    bool grow = (tm[0] > m_run[0] + THR2) | (tm[1] > m_run[1] + THR2) |
                (tm[2] > m_run[2] + THR2) | (tm[3] > m_run[3] + THR2);
    if (__any(grow)) {
      #pragma unroll
      for (int d = 1; d < 16; d <<= 1) {
        #pragma unroll
        for (int j = 0; j < 4; ++j) tm[j] = fmaxf(tm[j], __shfl_xor(tm[j], d));
      }
      #pragma unroll
      for (int j = 0; j < 4; ++j) {
        float mn = fmaxf(m_run[j], tm[j]);
        float al = exp2f(m_run[j] - mn);
        m_run[j] = mn;
        lsum[j] *= al;
        oacc[0][j] *= al; oacc[1][j] *= al; oacc[2][j] *= al; oacc[3][j] *= al;
      }
    }
    bf16_t* pw = sP[w];
    #pragma unroll
    for (int n = 0; n < 4; ++n) {
      int cg = n*2 + (r >> 3);
      #pragma unroll
      for (int j = 0; j < 4; ++j) {
        float p = exp2f(s[n][j] - m_run[j]);
        lsum[j] += p;
        int row = kg*4 + j;
        pw[row*64 + ((cg ^ (row & 7)) * 8) + r7] = (bf16_t)p;
      }
    }
    bf16x8 pa[2];
    #pragma unroll
    for (int c = 0; c < 2; ++c)
      pa[c] = *(const bf16x8*)&sP[w][r*64 + (((c*4 + kg) ^ r7) * 8)];
    #pragma unroll
    for (int n = 0; n < 4; ++n) {
      #pragma unroll
      for (int c = 0; c < 2; ++c) {
        bf16x8 vf = *(const bf16x8*)&Vt[(n*16 + r)*64 + (((c*4 + kg) ^ r7) * 8)];
        oacc[n] = MFMA_BF16(pa[c], vf, oacc[n]);
      }
    }
    __builtin_amdgcn_s_barrier();
  }

  #pragma unroll
  for (int d = 1; d < 16; d <<= 1) {
    #pragma unroll
    for (int j = 0; j < 4; ++j) lsum[j] += __shfl_xor(lsum[j], d);
  }
  float rcp[4];
  #pragma unroll
  for (int j = 0; j < 4; ++j) rcp[j] = 1.0f / lsum[j];
  #pragma unroll
  for (int n = 0; n < 4; ++n) {
    #pragma unroll
    for (int j = 0; j < 4; ++j) {
      int q = qt*64 + w*16 + kg*4 + j;
      int d = h*HDIM + n*16 + r;
      ob[(size_t)(b*SEQ + q) * D_MODEL + d] = f2bf(oacc[n][j] * rcp[j]);
    }
  }
}

// ---------------- launch ----------------
extern "C" void kernel_launch(void* const* d_in, const int* in_sizes, int n_in,
                              void* d_out, int out_size, void* d_ws, size_t ws_size,
                              hipStream_t stream) {
  const float* x   = (const float*)d_in[0];
  const int*  mask = (const int*)d_in[1];
  const float* Wq = (const float*)d_in[2];  const float* bq = (const float*)d_in[3];
  const float* Wk = (const float*)d_in[4];  const float* bk = (const float*)d_in[5];
  const float* Wv = (const float*)d_in[6];  const float* bv = (const float*)d_in[7];
  const float* Wo = (const float*)d_in[8];  const float* bo = (const float*)d_in[9];
  const float* W1 = (const float*)d_in[10]; const float* b1 = (const float*)d_in[11];
  const float* W2 = (const float*)d_in[12]; const float* b2 = (const float*)d_in[13];
  const float* g1 = (const float*)d_in[14]; const float* be1 = (const float*)d_in[15];
  const float* g2 = (const float*)d_in[16]; const float* be2 = (const float*)d_in[17];

  const size_t MB = 1u << 20;
  char* ws = (char*)d_ws;
  u16*  hln  = (u16*)(ws);              // 16MB  (LN1 out; later reused: vt, then LN2 out)
  u16*  vt   = (u16*)(ws);              // 16MB  V^T [b,h,d,key] — overwrites hln after QKV
  u16*  qb   = (u16*)(ws + 16*MB);      // 16MB
  u16*  kb   = (u16*)(ws + 32*MB);      // 16MB
  u16*  vb   = (u16*)(ws + 48*MB);      // 16MB
  u16*  attn = (u16*)(ws + 64*MB);      // 16MB
  u16*  ff1  = (u16*)(ws + 16*MB);      // 64MB, reuses q/k/v/attn region
  float* x2  = (float*)(ws + 80*MB);    // 32MB
  u16*  WqT  = (u16*)(ws + 112*MB);
  u16*  WkT  = (u16*)(ws + 114*MB);
  u16*  WvT  = (u16*)(ws + 116*MB);
  u16*  WoT  = (u16*)(ws + 118*MB);
  u16*  W1T  = (u16*)(ws + 120*MB);     // [4096,1024] 8MB
  u16*  W2T  = (u16*)(ws + 128*MB);     // [1024,4096] 8MB

  dim3 tb(256);
  wt_kernel<<<dim3(1024/32, 1024/32), tb, 0, stream>>>(Wq, WqT, 1024, 1024);
  wt_kernel<<<dim3(1024/32, 1024/32), tb, 0, stream>>>(Wk, WkT, 1024, 1024);
  wt_kernel<<<dim3(1024/32, 1024/32), tb, 0, stream>>>(Wv, WvT, 1024, 1024);
  wt_kernel<<<dim3(1024/32, 1024/32), tb, 0, stream>>>(Wo, WoT, 1024, 1024);
  wt_kernel<<<dim3(4096/32, 1024/32), tb, 0, stream>>>(W1, W1T, 1024, 4096);
  wt_kernel<<<dim3(1024/32, 4096/32), tb, 0, stream>>>(W2, W2T, 4096, 1024);

  ln_kernel<<<ROWS, tb, 0, stream>>>(x, g1, be1, hln);

  dim3 gb(512);
  gemm256<0><<<dim3(1024/256, ROWS/128), gb, 0, stream>>>(hln, WqT, bq, nullptr, qb, ROWS, 1024, 1024);
  gemm256<0><<<dim3(1024/256, ROWS/128), gb, 0, stream>>>(hln, WkT, bk, nullptr, kb, ROWS, 1024, 1024);
  gemm256<0><<<dim3(1024/256, ROWS/128), gb, 0, stream>>>(hln, WvT, bv, nullptr, vb, ROWS, 1024, 1024);

  vtrans_kernel<<<dim3(SEQ/64, BATCH*NHEAD), tb, 0, stream>>>(vb, vt);

  attn_kernel<<<dim3(SEQ/64, BATCH*NHEAD), tb, 0, stream>>>(qb, kb, vt, mask, attn);

  gemm256<1><<<dim3(1024/256, ROWS/128), gb, 0, stream>>>(attn, WoT, bo, x, x2, ROWS, 1024, 1024);

  ln_kernel<<<ROWS, tb, 0, stream>>>(x2, g2, be2, hln);

  gemm256<2><<<dim3(4096/256, ROWS/128), gb, 0, stream>>>(hln, W1T, b1, nullptr, ff1, ROWS, 4096, 1024);

  gemm256<1><<<dim3(1024/256, ROWS/128), gb, 0, stream>>>(ff1, W2T, b2, x2, (float*)d_out, ROWS, 1024, 4096);
}